// Round 3
// baseline (553.920 us; speedup 1.0000x reference)
//
#include <hip/hip_runtime.h>

#define DEVINL __device__ __forceinline__

typedef __attribute__((ext_vector_type(8))) short bf16x8;
typedef __attribute__((ext_vector_type(4))) float f32x4;
typedef __attribute__((ext_vector_type(2))) unsigned int u32x2;

static constexpr int S = 4096;
static constexpr int D = 768;
static constexpr float POST_SCALE = 19.595917942265423f; // sqrt(384)
static constexpr int TSLICE = 1344;                      // 21*64; last slice 22*64

#define MFMA16(a, b, c) __builtin_amdgcn_mfma_f32_16x16x32_bf16((a), (b), (c), 0, 0, 0)

DEVINL unsigned short f2bf(float f) {
  union { float f; unsigned u; } v; v.f = f;
  unsigned r = (v.u + 0x7FFFu + ((v.u >> 16) & 1u)) >> 16;  // RNE
  return (unsigned short)r;
}

// ---------------- fp32 -> bf16 convert ----------------
__global__ void cvt_kernel(const float* __restrict__ src,
                           unsigned short* __restrict__ dst, int n4) {
  int i = blockIdx.x * blockDim.x + threadIdx.x;
  if (i >= n4) return;
  float4 v = reinterpret_cast<const float4*>(src)[i];
  ushort4 o;
  o.x = f2bf(v.x); o.y = f2bf(v.y); o.z = f2bf(v.z); o.w = f2bf(v.w);
  reinterpret_cast<ushort4*>(dst)[i] = o;
}

// ---------------- (a+b+c) fp32 -> bf16 ----------------
__global__ void addcvt3_kernel(const float* __restrict__ a,
                               const float* __restrict__ b,
                               const float* __restrict__ c,
                               unsigned short* __restrict__ dst, int n4) {
  int i = blockIdx.x * blockDim.x + threadIdx.x;
  if (i >= n4) return;
  float4 va = reinterpret_cast<const float4*>(a)[i];
  float4 vb = reinterpret_cast<const float4*>(b)[i];
  float4 vc = reinterpret_cast<const float4*>(c)[i];
  ushort4 o;
  o.x = f2bf(va.x + vb.x + vc.x); o.y = f2bf(va.y + vb.y + vc.y);
  o.z = f2bf(va.z + vb.z + vc.z); o.w = f2bf(va.w + vb.w + vc.w);
  reinterpret_cast<ushort4*>(dst)[i] = o;
}

// ---------------- bf16 transpose [S,D] -> [D,S] ----------------
__global__ void transpose_kernel(const unsigned short* __restrict__ in,
                                 unsigned short* __restrict__ out) {
  __shared__ unsigned short tile[32][33];
  int d0 = blockIdx.x * 32, t0 = blockIdx.y * 32;
  int tx = threadIdx.x, ty = threadIdx.y;  // block (32,8)
#pragma unroll
  for (int j = 0; j < 4; j++)
    tile[ty + j * 8][tx] = in[(size_t)(t0 + ty + j * 8) * D + d0 + tx];
  __syncthreads();
#pragma unroll
  for (int j = 0; j < 4; j++)
    out[(size_t)(d0 + ty + j * 8) * S + t0 + tx] = tile[tx][ty + j * 8];
}

// ---------------- GEMM: C[M,N] = A[M,K] @ B[N,K]^T + bias ----------------
template <bool F32OUT>
__global__ __launch_bounds__(256) void gemm_bt(
    const unsigned short* __restrict__ A, const unsigned short* __restrict__ B,
    const float* __restrict__ bias, void* __restrict__ Cout,
    int M, int N, int K) {
  int w = threadIdx.x >> 6, lane = threadIdx.x & 63;
  int r = lane & 15, b = lane >> 4;
  int rowbase = blockIdx.y * 128 + (w >> 1) * 64;
  int colbase = blockIdx.x * 128 + (w & 1) * 64;
  f32x4 acc[4][4] = {};
  for (int kk = 0; kk < K; kk += 32) {
    bf16x8 af[4], bfr[4];
#pragma unroll
    for (int m = 0; m < 4; m++)
      af[m] = *reinterpret_cast<const bf16x8*>(A + (size_t)(rowbase + m * 16 + r) * K + kk + b * 8);
#pragma unroll
    for (int n = 0; n < 4; n++)
      bfr[n] = *reinterpret_cast<const bf16x8*>(B + (size_t)(colbase + n * 16 + r) * K + kk + b * 8);
#pragma unroll
    for (int m = 0; m < 4; m++)
#pragma unroll
      for (int n = 0; n < 4; n++)
        acc[m][n] = MFMA16(af[m], bfr[n], acc[m][n]);
  }
#pragma unroll
  for (int m = 0; m < 4; m++)
#pragma unroll
    for (int n = 0; n < 4; n++)
#pragma unroll
      for (int i = 0; i < 4; i++) {
        int row = rowbase + m * 16 + b * 4 + i;
        int col = colbase + n * 16 + r;
        float v = acc[m][n][i] + bias[col];
        if (F32OUT)
          reinterpret_cast<float*>(Cout)[(size_t)row * N + col] = v;
        else
          reinterpret_cast<unsigned short*>(Cout)[(size_t)row * N + col] = f2bf(v);
      }
}

// ---------------- fused attention v2 ----------------
// Block: 16 s-rows, t-slice [tbeg,tend). 4 waves; each wave owns a 16-t
// sub-chunk per 64-t iteration and computes ALL 12 heads' scores on its
// 16t x 16s tile (C rows = t), so the 12 softmax values per (s,t) are
// lane-local: in-register softmax, no LDS for scores. P goes to swizzled
// LDS in PV-A layout; PV phase splits 3 heads/wave over the 64-t chunk.
__global__ __launch_bounds__(256, 3) void attn_kernel(
    const unsigned short* __restrict__ Qb, const unsigned short* __restrict__ Kb,
    const unsigned short* __restrict__ Vt, float* __restrict__ Opart) {
  __shared__ unsigned short K_lds[16 * 768];    // 24 KB, XOR-swizzled rows
  __shared__ unsigned short P_lds[12 * 16 * 64];// 24 KB, XOR-swizzled rows

  const int s0 = blockIdx.x * 16;
  const int tbeg = blockIdx.y * TSLICE;
  const int tend = (blockIdx.y == 2) ? S : tbeg + TSLICE;
  const int w = threadIdx.x >> 6, lane = threadIdx.x & 63;
  const int r = lane & 15, b = lane >> 4;
  const int swzr = (r & 7) << 4;

  // ---- stage K rows [s0, s0+16) x 768 into swizzled LDS ----
  {
    char* Kc = reinterpret_cast<char*>(K_lds);
    for (int c = threadIdx.x; c < 16 * 96; c += 256) {
      int row = c / 96, col8 = c % 96;
      bf16x8 v = *reinterpret_cast<const bf16x8*>(Kb + (size_t)(s0 + row) * D + col8 * 8);
      *reinterpret_cast<bf16x8*>(Kc + ((row * 1536 + col8 * 16) ^ ((row & 7) << 4))) = v;
    }
  }
  __syncthreads();

  const char* kb0 = reinterpret_cast<const char*>(K_lds) + r * 1536 + ((b * 16) ^ swzr);
  const char* kb1 = reinterpret_cast<const char*>(K_lds) + r * 1536 + ((64 + b * 16) ^ swzr);
  char* pw = reinterpret_cast<char*>(P_lds) + r * 128 + ((w * 32 + b * 8) ^ swzr);
  const char* pr0 = reinterpret_cast<const char*>(P_lds) + (w * 3) * 2048 + r * 128 + ((b * 16) ^ swzr);
  const char* pr1 = reinterpret_cast<const char*>(P_lds) + (w * 3) * 2048 + r * 128 + ((64 + b * 16) ^ swzr);

  f32x4 oacc[3][4] = {};

  for (int t0 = tbeg; t0 < tend; t0 += 64) {
    const int tw = t0 + w * 16;  // this wave's t sub-chunk
    const unsigned short* qrow = Qb + (size_t)(tw + r) * D + b * 8;

    // ---- scores: all 12 heads on 16t x 16s tile, C[row=t][col=s] ----
    f32x4 acc[12];
#pragma unroll
    for (int h = 0; h < 12; h++) {
      f32x4 c = {};
      bf16x8 qf0 = *reinterpret_cast<const bf16x8*>(qrow + h * 64);
      bf16x8 kf0 = *reinterpret_cast<const bf16x8*>(kb0 + h * 128);
      c = MFMA16(qf0, kf0, c);
      bf16x8 qf1 = *reinterpret_cast<const bf16x8*>(qrow + h * 64 + 32);
      bf16x8 kf1 = *reinterpret_cast<const bf16x8*>(kb1 + h * 128);
      c = MFMA16(qf1, kf1, c);
      acc[h] = c;
    }

    // ---- in-register softmax over h (4 independent t-points per lane) ----
    float m0, m1, m2, m3, s0f, s1f, s2f, s3f;
    m0 = acc[0][0]; m1 = acc[0][1]; m2 = acc[0][2]; m3 = acc[0][3];
#pragma unroll
    for (int h = 1; h < 12; h++) {
      m0 = fmaxf(m0, acc[h][0]); m1 = fmaxf(m1, acc[h][1]);
      m2 = fmaxf(m2, acc[h][2]); m3 = fmaxf(m3, acc[h][3]);
    }
    s0f = s1f = s2f = s3f = 0.f;
#pragma unroll
    for (int h = 0; h < 12; h++) {
      acc[h][0] = __expf(acc[h][0] - m0); s0f += acc[h][0];
      acc[h][1] = __expf(acc[h][1] - m1); s1f += acc[h][1];
      acc[h][2] = __expf(acc[h][2] - m2); s2f += acc[h][2];
      acc[h][3] = __expf(acc[h][3] - m3); s3f += acc[h][3];
    }
    s0f = POST_SCALE * __builtin_amdgcn_rcpf(s0f);
    s1f = POST_SCALE * __builtin_amdgcn_rcpf(s1f);
    s2f = POST_SCALE * __builtin_amdgcn_rcpf(s2f);
    s3f = POST_SCALE * __builtin_amdgcn_rcpf(s3f);

    // ---- pack P to bf16 (t-contiguous per lane) and write to LDS ----
#pragma unroll
    for (int h = 0; h < 12; h++) {
      u32x2 pk;
      float p0 = acc[h][0] * s0f, p1 = acc[h][1] * s1f;
      float p2 = acc[h][2] * s2f, p3 = acc[h][3] * s3f;
      asm("v_cvt_pk_bf16_f32 %0, %1, %2" : "=v"(pk.x) : "v"(p0), "v"(p1));
      asm("v_cvt_pk_bf16_f32 %0, %1, %2" : "=v"(pk.y) : "v"(p2), "v"(p3));
      *reinterpret_cast<u32x2*>(pw + h * 2048) = pk;
    }
    __syncthreads();

    // ---- PV: 3 heads/wave, O[16s][64d] += P[16s][64t] @ V[64t][64d] ----
#pragma unroll
    for (int hh = 0; hh < 3; hh++) {
      const int h = w * 3 + hh;
      bf16x8 pf0 = *reinterpret_cast<const bf16x8*>(pr0 + hh * 2048);
      bf16x8 pf1 = *reinterpret_cast<const bf16x8*>(pr1 + hh * 2048);
      const unsigned short* vp = Vt + (size_t)(h * 64 + r) * S + t0 + b * 8;
#pragma unroll
      for (int ds = 0; ds < 4; ds++) {
        bf16x8 vf0 = *reinterpret_cast<const bf16x8*>(vp + (size_t)ds * 16 * S);
        bf16x8 vf1 = *reinterpret_cast<const bf16x8*>(vp + (size_t)ds * 16 * S + 32);
        oacc[hh][ds] = MFMA16(pf0, vf0, oacc[hh][ds]);
        oacc[hh][ds] = MFMA16(pf1, vf1, oacc[hh][ds]);
      }
    }
    __syncthreads();  // P_lds reused next chunk
  }

  float* Op = Opart + (size_t)blockIdx.y * S * D;
#pragma unroll
  for (int hh = 0; hh < 3; hh++)
#pragma unroll
    for (int ds = 0; ds < 4; ds++)
#pragma unroll
      for (int i = 0; i < 4; i++) {
        int row = s0 + b * 4 + i;
        int col = (w * 3 + hh) * 64 + ds * 16 + r;
        Op[(size_t)row * D + col] = oacc[hh][ds][i];
      }
}

extern "C" void kernel_launch(void* const* d_in, const int* in_sizes, int n_in,
                              void* d_out, int out_size, void* d_ws, size_t ws_size,
                              hipStream_t stream) {
  const float* x  = (const float*)d_in[0];
  const float* Wq = (const float*)d_in[1];
  const float* bq = (const float*)d_in[2];
  const float* Wk = (const float*)d_in[3];
  const float* bk = (const float*)d_in[4];
  const float* Wv = (const float*)d_in[5];
  const float* bv = (const float*)d_in[6];
  const float* Wo = (const float*)d_in[7];
  const float* bo = (const float*)d_in[8];
  float* out = (float*)d_out;

  char* ws = (char*)d_ws;
  size_t off = 0;
  auto walloc = [&](size_t bytes) -> void* {
    void* p = ws + off;
    off += (bytes + 255) & ~(size_t)255;
    return p;
  };
  unsigned short* xb  = (unsigned short*)walloc((size_t)S * D * 2);
  unsigned short* Wqb = (unsigned short*)walloc((size_t)D * D * 2);
  unsigned short* Wkb = (unsigned short*)walloc((size_t)D * D * 2);
  unsigned short* Wvb = (unsigned short*)walloc((size_t)D * D * 2);
  unsigned short* Wob = (unsigned short*)walloc((size_t)D * D * 2);
  unsigned short* Qb  = (unsigned short*)walloc((size_t)S * D * 2);
  unsigned short* Kb  = (unsigned short*)walloc((size_t)S * D * 2);
  unsigned short* Vb  = (unsigned short*)walloc((size_t)S * D * 2);
  unsigned short* Vt  = (unsigned short*)walloc((size_t)S * D * 2);
  unsigned short* Ob  = (unsigned short*)walloc((size_t)S * D * 2);
  float* Opart = (float*)walloc((size_t)3 * S * D * 4);

  int n4;
  n4 = S * D / 4;
  cvt_kernel<<<(n4 + 255) / 256, 256, 0, stream>>>(x, xb, n4);
  n4 = D * D / 4;
  cvt_kernel<<<(n4 + 255) / 256, 256, 0, stream>>>(Wq, Wqb, n4);
  cvt_kernel<<<(n4 + 255) / 256, 256, 0, stream>>>(Wk, Wkb, n4);
  cvt_kernel<<<(n4 + 255) / 256, 256, 0, stream>>>(Wv, Wvb, n4);
  cvt_kernel<<<(n4 + 255) / 256, 256, 0, stream>>>(Wo, Wob, n4);

  dim3 gg(D / 128, S / 128);  // (6, 32)
  gemm_bt<false><<<gg, 256, 0, stream>>>(xb, Wqb, bq, Qb, S, D, D);
  gemm_bt<false><<<gg, 256, 0, stream>>>(xb, Wkb, bk, Kb, S, D, D);
  gemm_bt<false><<<gg, 256, 0, stream>>>(xb, Wvb, bv, Vb, S, D, D);

  transpose_kernel<<<dim3(D / 32, S / 32), dim3(32, 8), 0, stream>>>(Vb, Vt);

  attn_kernel<<<dim3(S / 16, 3), 256, 0, stream>>>(Qb, Kb, Vt, Opart);

  n4 = S * D / 4;
  addcvt3_kernel<<<(n4 + 255) / 256, 256, 0, stream>>>(
      Opart, Opart + (size_t)S * D, Opart + (size_t)2 * S * D, Ob, n4);

  gemm_bt<true><<<gg, 256, 0, stream>>>(Ob, Wob, bo, out, S, D, D);
}

// Round 5
// 485.242 us; speedup vs baseline: 1.1415x; 1.1415x over previous
//
#include <hip/hip_runtime.h>

#define DEVINL __device__ __forceinline__

typedef __attribute__((ext_vector_type(8))) short bf16x8;
typedef __attribute__((ext_vector_type(4))) float f32x4;
typedef __attribute__((ext_vector_type(2))) unsigned int u32x2;

static constexpr int S = 4096;
static constexpr int D = 768;
static constexpr float POST_SCALE = 19.595917942265423f; // sqrt(384)

#define MFMA16(a, b, c) __builtin_amdgcn_mfma_f32_16x16x32_bf16((a), (b), (c), 0, 0, 0)

DEVINL unsigned short f2bf(float f) {
  union { float f; unsigned u; } v; v.f = f;
  unsigned r = (v.u + 0x7FFFu + ((v.u >> 16) & 1u)) >> 16;  // RNE
  return (unsigned short)r;
}

// ---------------- fp32 -> bf16 convert ----------------
__global__ void cvt_kernel(const float* __restrict__ src,
                           unsigned short* __restrict__ dst, int n4) {
  int i = blockIdx.x * blockDim.x + threadIdx.x;
  if (i >= n4) return;
  float4 v = reinterpret_cast<const float4*>(src)[i];
  ushort4 o;
  o.x = f2bf(v.x); o.y = f2bf(v.y); o.z = f2bf(v.z); o.w = f2bf(v.w);
  reinterpret_cast<ushort4*>(dst)[i] = o;
}

// ---------------- (a+b+c+d) fp32 -> bf16 ----------------
__global__ void addcvt4_kernel(const float* __restrict__ a,
                               const float* __restrict__ b,
                               const float* __restrict__ c,
                               const float* __restrict__ d,
                               unsigned short* __restrict__ dst, int n4) {
  int i = blockIdx.x * blockDim.x + threadIdx.x;
  if (i >= n4) return;
  float4 va = reinterpret_cast<const float4*>(a)[i];
  float4 vb = reinterpret_cast<const float4*>(b)[i];
  float4 vc = reinterpret_cast<const float4*>(c)[i];
  float4 vd = reinterpret_cast<const float4*>(d)[i];
  ushort4 o;
  o.x = f2bf(va.x + vb.x + vc.x + vd.x);
  o.y = f2bf(va.y + vb.y + vc.y + vd.y);
  o.z = f2bf(va.z + vb.z + vc.z + vd.z);
  o.w = f2bf(va.w + vb.w + vc.w + vd.w);
  reinterpret_cast<ushort4*>(dst)[i] = o;
}

// ---------------- bf16 transpose [S,D] -> [D,S] ----------------
__global__ void transpose_kernel(const unsigned short* __restrict__ in,
                                 unsigned short* __restrict__ out) {
  __shared__ unsigned short tile[32][33];
  int d0 = blockIdx.x * 32, t0 = blockIdx.y * 32;
  int tx = threadIdx.x, ty = threadIdx.y;  // block (32,8)
#pragma unroll
  for (int j = 0; j < 4; j++)
    tile[ty + j * 8][tx] = in[(size_t)(t0 + ty + j * 8) * D + d0 + tx];
  __syncthreads();
#pragma unroll
  for (int j = 0; j < 4; j++)
    out[(size_t)(d0 + ty + j * 8) * S + t0 + tx] = tile[tx][ty + j * 8];
}

// ---------------- GEMM: C[M,N] = A[M,K] @ B[N,K]^T + bias ----------------
template <bool F32OUT>
__global__ __launch_bounds__(256) void gemm_bt(
    const unsigned short* __restrict__ A, const unsigned short* __restrict__ B,
    const float* __restrict__ bias, void* __restrict__ Cout,
    int M, int N, int K) {
  int w = threadIdx.x >> 6, lane = threadIdx.x & 63;
  int r = lane & 15, b = lane >> 4;
  int rowbase = blockIdx.y * 128 + (w >> 1) * 64;
  int colbase = blockIdx.x * 128 + (w & 1) * 64;
  f32x4 acc[4][4] = {};
  for (int kk = 0; kk < K; kk += 32) {
    bf16x8 af[4], bfr[4];
#pragma unroll
    for (int m = 0; m < 4; m++)
      af[m] = *reinterpret_cast<const bf16x8*>(A + (size_t)(rowbase + m * 16 + r) * K + kk + b * 8);
#pragma unroll
    for (int n = 0; n < 4; n++)
      bfr[n] = *reinterpret_cast<const bf16x8*>(B + (size_t)(colbase + n * 16 + r) * K + kk + b * 8);
#pragma unroll
    for (int m = 0; m < 4; m++)
#pragma unroll
      for (int n = 0; n < 4; n++)
        acc[m][n] = MFMA16(af[m], bfr[n], acc[m][n]);
  }
#pragma unroll
  for (int m = 0; m < 4; m++)
#pragma unroll
    for (int n = 0; n < 4; n++)
#pragma unroll
      for (int i = 0; i < 4; i++) {
        int row = rowbase + m * 16 + b * 4 + i;
        int col = colbase + n * 16 + r;
        float v = acc[m][n][i] + bias[col];
        if (F32OUT)
          reinterpret_cast<float*>(Cout)[(size_t)row * N + col] = v;
        else
          reinterpret_cast<unsigned short*>(Cout)[(size_t)row * N + col] = f2bf(v);
      }
}

// ---------------- fused attention v3 ----------------
// Block: 64 s-rows, 12 heads, t-slice of 1024, 8 waves. Per 32-t chunk:
//   score phase: wave (si = w&3, ti = w>>2) computes a 16t x 16s tile for
//     ALL 12 heads (A=Q from prefetched regs, B=K from swizzled LDS).
//     C layout: row=t, col=s -> 12 head-scores per (s,t) are lane-local:
//     in-register softmax, cvt_pk to bf16, write P[12][64s][32t] to LDS.
//   PV phase: wave (sg = w>>2, hg = w&3) computes O[32s x 3 heads x 64d]
//     using P from LDS (A) and Vt fragments prefetched into regs before
//     the softmax (latency hidden under softmax + barrier).
__global__ __launch_bounds__(512, 2) void attn_kernel(
    const unsigned short* __restrict__ Qb, const unsigned short* __restrict__ Kb,
    const unsigned short* __restrict__ Vt, float* __restrict__ Opart) {
  __shared__ unsigned short K_lds[64 * 768];      // 96 KB, row-XOR-swizzled
  __shared__ unsigned short P_lds[12 * 64 * 32];  // 48 KB, row-XOR-swizzled

  const int s0 = blockIdx.x * 64;
  const int tbeg = blockIdx.y * 1024;
  const int w = threadIdx.x >> 6, lane = threadIdx.x & 63;
  const int r = lane & 15, b = lane >> 4;

  char* Kc = reinterpret_cast<char*>(K_lds);
  char* Pc = reinterpret_cast<char*>(P_lds);

  // ---- stage K rows [s0, s0+64) x 768 into swizzled LDS ----
  for (int idx = threadIdx.x; idx < 64 * 96; idx += 512) {
    int row = idx / 96, col8 = idx % 96;
    bf16x8 v = *reinterpret_cast<const bf16x8*>(Kb + (size_t)(s0 + row) * D + col8 * 8);
    *reinterpret_cast<bf16x8*>(Kc + row * 1536 + ((col8 * 16) ^ ((row & 7) << 4))) = v;
  }
  __syncthreads();

  // score-phase constants: wave -> (si, ti)
  const int si = w & 3, ti = w >> 2;
  const char* kbase = Kc + (si * 16 + r) * 1536;
  const int kswz = (r & 7) << 4;
  char* pwb = Pc + (si * 16 + r) * 64 + ((ti * 32 + b * 8) ^ ((r & 3) << 4));

  // PV-phase constants: wave -> (sg, hg)
  const int sg = w >> 2, hg = w & 3;
  const char* prb = Pc + (size_t)(hg * 3) * 4096 + (sg * 32 + r) * 64 +
                    ((b * 16) ^ ((r & 3) << 4));
  const unsigned short* vbase = Vt + (size_t)(hg * 3 * 64 + r) * S + b * 8;

  f32x4 oacc[2][3][4] = {};

  for (int t0 = tbeg; t0 < tbeg + 1024; t0 += 32) {
    const unsigned short* qrow = Qb + (size_t)(t0 + ti * 16 + r) * D + b * 8;

    // ---- score phase: prefetched Q (6-deep), K from LDS ----
    bf16x8 qreg[6][2];
#pragma unroll
    for (int h = 0; h < 6; h++) {
      qreg[h][0] = *reinterpret_cast<const bf16x8*>(qrow + h * 64);
      qreg[h][1] = *reinterpret_cast<const bf16x8*>(qrow + h * 64 + 32);
    }
    f32x4 acc[12];
#pragma unroll
    for (int h = 0; h < 6; h++) {
      bf16x8 k0 = *reinterpret_cast<const bf16x8*>(kbase + ((h * 128 + b * 16) ^ kswz));
      bf16x8 k1 = *reinterpret_cast<const bf16x8*>(kbase + ((h * 128 + 64 + b * 16) ^ kswz));
      f32x4 c = {};
      c = MFMA16(qreg[h][0], k0, c);
      c = MFMA16(qreg[h][1], k1, c);
      acc[h] = c;
      qreg[h][0] = *reinterpret_cast<const bf16x8*>(qrow + (h + 6) * 64);
      qreg[h][1] = *reinterpret_cast<const bf16x8*>(qrow + (h + 6) * 64 + 32);
    }
#pragma unroll
    for (int h = 0; h < 6; h++) {
      bf16x8 k0 = *reinterpret_cast<const bf16x8*>(kbase + (((h + 6) * 128 + b * 16) ^ kswz));
      bf16x8 k1 = *reinterpret_cast<const bf16x8*>(kbase + (((h + 6) * 128 + 64 + b * 16) ^ kswz));
      f32x4 c = {};
      c = MFMA16(qreg[h][0], k0, c);
      c = MFMA16(qreg[h][1], k1, c);
      acc[h + 6] = c;
    }

    // ---- issue Vt prefetch now; softmax + barrier hide its latency ----
    bf16x8 vreg[3][4];
#pragma unroll
    for (int hh = 0; hh < 3; hh++)
#pragma unroll
      for (int dt = 0; dt < 4; dt++)
        vreg[hh][dt] = *reinterpret_cast<const bf16x8*>(
            vbase + (size_t)(hh * 64 + dt * 16) * S + t0);

    // ---- in-register softmax over h (4 t-points per lane) ----
    float m0, m1, m2, m3, s0f, s1f, s2f, s3f;
    m0 = acc[0][0]; m1 = acc[0][1]; m2 = acc[0][2]; m3 = acc[0][3];
#pragma unroll
    for (int h = 1; h < 12; h++) {
      m0 = fmaxf(m0, acc[h][0]); m1 = fmaxf(m1, acc[h][1]);
      m2 = fmaxf(m2, acc[h][2]); m3 = fmaxf(m3, acc[h][3]);
    }
    s0f = s1f = s2f = s3f = 0.f;
#pragma unroll
    for (int h = 0; h < 12; h++) {
      acc[h][0] = __expf(acc[h][0] - m0); s0f += acc[h][0];
      acc[h][1] = __expf(acc[h][1] - m1); s1f += acc[h][1];
      acc[h][2] = __expf(acc[h][2] - m2); s2f += acc[h][2];
      acc[h][3] = __expf(acc[h][3] - m3); s3f += acc[h][3];
    }
    s0f = POST_SCALE * __builtin_amdgcn_rcpf(s0f);
    s1f = POST_SCALE * __builtin_amdgcn_rcpf(s1f);
    s2f = POST_SCALE * __builtin_amdgcn_rcpf(s2f);
    s3f = POST_SCALE * __builtin_amdgcn_rcpf(s3f);

    // ---- pack P to bf16 and write to swizzled LDS ----
#pragma unroll
    for (int h = 0; h < 12; h++) {
      u32x2 pk;
      float p0 = acc[h][0] * s0f, p1 = acc[h][1] * s1f;
      float p2 = acc[h][2] * s2f, p3 = acc[h][3] * s3f;
      asm("v_cvt_pk_bf16_f32 %0, %1, %2" : "=v"(pk.x) : "v"(p0), "v"(p1));
      asm("v_cvt_pk_bf16_f32 %0, %1, %2" : "=v"(pk.y) : "v"(p2), "v"(p3));
      *reinterpret_cast<u32x2*>(pwb + h * 4096) = pk;
    }
    __syncthreads();

    // ---- PV: O[2 s-subtiles][3 heads][4 d-tiles] += P @ V ----
#pragma unroll
    for (int st = 0; st < 2; st++) {
#pragma unroll
      for (int hh = 0; hh < 3; hh++) {
        bf16x8 pf = *reinterpret_cast<const bf16x8*>(prb + st * 1024 + hh * 4096);
#pragma unroll
        for (int dt = 0; dt < 4; dt++)
          oacc[st][hh][dt] = MFMA16(pf, vreg[hh][dt], oacc[st][hh][dt]);
      }
    }
    __syncthreads();  // P_lds reused next chunk
  }

  float* Op = Opart + (size_t)blockIdx.y * S * D;
#pragma unroll
  for (int st = 0; st < 2; st++)
#pragma unroll
    for (int hh = 0; hh < 3; hh++)
#pragma unroll
      for (int dt = 0; dt < 4; dt++)
#pragma unroll
        for (int i = 0; i < 4; i++) {
          int row = s0 + sg * 32 + st * 16 + b * 4 + i;
          int col = (hg * 3 + hh) * 64 + dt * 16 + r;
          Op[(size_t)row * D + col] = oacc[st][hh][dt][i];
        }
}

extern "C" void kernel_launch(void* const* d_in, const int* in_sizes, int n_in,
                              void* d_out, int out_size, void* d_ws, size_t ws_size,
                              hipStream_t stream) {
  const float* x  = (const float*)d_in[0];
  const float* Wq = (const float*)d_in[1];
  const float* bq = (const float*)d_in[2];
  const float* Wk = (const float*)d_in[3];
  const float* bk = (const float*)d_in[4];
  const float* Wv = (const float*)d_in[5];
  const float* bv = (const float*)d_in[6];
  const float* Wo = (const float*)d_in[7];
  const float* bo = (const float*)d_in[8];
  float* out = (float*)d_out;

  char* ws = (char*)d_ws;
  size_t off = 0;
  auto walloc = [&](size_t bytes) -> void* {
    void* p = ws + off;
    off += (bytes + 255) & ~(size_t)255;
    return p;
  };
  unsigned short* xb  = (unsigned short*)walloc((size_t)S * D * 2);
  unsigned short* Wqb = (unsigned short*)walloc((size_t)D * D * 2);
  unsigned short* Wkb = (unsigned short*)walloc((size_t)D * D * 2);
  unsigned short* Wvb = (unsigned short*)walloc((size_t)D * D * 2);
  unsigned short* Wob = (unsigned short*)walloc((size_t)D * D * 2);
  unsigned short* Qb  = (unsigned short*)walloc((size_t)S * D * 2);
  unsigned short* Kb  = (unsigned short*)walloc((size_t)S * D * 2);
  unsigned short* Vb  = (unsigned short*)walloc((size_t)S * D * 2);
  unsigned short* Vt  = (unsigned short*)walloc((size_t)S * D * 2);
  unsigned short* Ob  = (unsigned short*)walloc((size_t)S * D * 2);
  float* Opart = (float*)walloc((size_t)4 * S * D * 4);

  int n4;
  n4 = S * D / 4;
  cvt_kernel<<<(n4 + 255) / 256, 256, 0, stream>>>(x, xb, n4);
  n4 = D * D / 4;
  cvt_kernel<<<(n4 + 255) / 256, 256, 0, stream>>>(Wq, Wqb, n4);
  cvt_kernel<<<(n4 + 255) / 256, 256, 0, stream>>>(Wk, Wkb, n4);
  cvt_kernel<<<(n4 + 255) / 256, 256, 0, stream>>>(Wv, Wvb, n4);
  cvt_kernel<<<(n4 + 255) / 256, 256, 0, stream>>>(Wo, Wob, n4);

  dim3 gg(D / 128, S / 128);  // (6, 32)
  gemm_bt<false><<<gg, 256, 0, stream>>>(xb, Wqb, bq, Qb, S, D, D);
  gemm_bt<false><<<gg, 256, 0, stream>>>(xb, Wkb, bk, Kb, S, D, D);
  gemm_bt<false><<<gg, 256, 0, stream>>>(xb, Wvb, bv, Vb, S, D, D);

  transpose_kernel<<<dim3(D / 32, S / 32), dim3(32, 8), 0, stream>>>(Vb, Vt);

  attn_kernel<<<dim3(S / 64, 4), 512, 0, stream>>>(Qb, Kb, Vt, Opart);

  n4 = S * D / 4;
  addcvt4_kernel<<<(n4 + 255) / 256, 256, 0, stream>>>(
      Opart, Opart + (size_t)S * D, Opart + (size_t)2 * S * D,
      Opart + (size_t)3 * S * D, Ob, n4);

  gemm_bt<true><<<gg, 256, 0, stream>>>(Ob, Wob, bo, out, S, D, D);
}